// Round 2
// baseline (611.366 us; speedup 1.0000x reference)
//
#include <hip/hip_runtime.h>

#define HD 2048
#define FD 8192
#define NE 8
#define CAP 512

typedef __attribute__((ext_vector_type(4))) float f32x4;
typedef __attribute__((ext_vector_type(8))) __bf16 bf16x8;

__device__ __forceinline__ void gload_lds16(const __bf16* g, __bf16* l) {
    __builtin_amdgcn_global_load_lds(
        (const __attribute__((address_space(1))) void*)g,
        (__attribute__((address_space(3))) void*)l, 16, 0, 0);
}

// ---------------- weight f32 -> bf16 conversion ----------------
__global__ __launch_bounds__(256) void cvt_k(const float* __restrict__ src,
                                             __bf16* __restrict__ dst, int n8) {
    int i = blockIdx.x * 256 + threadIdx.x;
    if (i >= n8) return;
    const float* s = src + (size_t)i * 8;
    f32x4 a = *(const f32x4*)s;
    f32x4 b = *(const f32x4*)(s + 4);
    bf16x8 o;
    o[0] = (__bf16)a[0]; o[1] = (__bf16)a[1]; o[2] = (__bf16)a[2]; o[3] = (__bf16)a[3];
    o[4] = (__bf16)b[0]; o[5] = (__bf16)b[1]; o[6] = (__bf16)b[2]; o[7] = (__bf16)b[3];
    *(bf16x8*)(dst + (size_t)i * 8) = o;
}

// ---------------- router: f64 logits, f32-prob top-2 with index tie-break ----------------
__global__ __launch_bounds__(256) void router_k(const float* __restrict__ x,
                                                const float* __restrict__ rw,
                                                int2* __restrict__ experts,
                                                float2* __restrict__ probs, int Ntok) {
    int wave = threadIdx.x >> 6, lane = threadIdx.x & 63;
    int n = blockIdx.x * 4 + wave;
    if (n >= Ntok) return;
    const float* xr = x + (size_t)n * HD;
    double acc[NE];
#pragma unroll
    for (int e = 0; e < NE; e++) acc[e] = 0.0;
    for (int i = 0; i < HD / 64; i++) {
        float xv = xr[lane + 64 * i];
#pragma unroll
        for (int e = 0; e < NE; e++)
            acc[e] += (double)xv * (double)rw[e * HD + lane + 64 * i];
    }
#pragma unroll
    for (int e = 0; e < NE; e++) {
        double v = acc[e];
        for (int off = 32; off > 0; off >>= 1) v += __shfl_xor(v, off);
        acc[e] = v;
    }
    if (lane == 0) {
        double mx = acc[0];
#pragma unroll
        for (int e = 1; e < NE; e++) mx = acc[e] > mx ? acc[e] : mx;
        double s = 0.0;
#pragma unroll
        for (int e = 0; e < NE; e++) s += exp(acc[e] - mx);
        float pf[NE];
#pragma unroll
        for (int e = 0; e < NE; e++) pf[e] = (float)(exp(acc[e] - mx) / s);
        int e0 = 0; float b0 = pf[0];
#pragma unroll
        for (int e = 1; e < NE; e++) if (pf[e] > b0) { b0 = pf[e]; e0 = e; }
        int e1 = -1; float b1 = -1.0f;
#pragma unroll
        for (int e = 0; e < NE; e++) if (e != e0 && pf[e] > b1) { b1 = pf[e]; e1 = e; }
        experts[n] = make_int2(e0, e1);
        probs[n] = make_float2(b0, b1);
    }
}

// ---------------- capacity scan (slot-major order), single block ----------------
__global__ __launch_bounds__(256) void scan_k(const int2* __restrict__ experts,
                                              int* __restrict__ dest,
                                              int* __restrict__ slot_token, int Ntok) {
    __shared__ int cnts[256][NE];
    int tid = threadIdx.x;
    for (int i = tid; i < NE * CAP; i += 256) slot_token[i] = -1;
    int per = (2 * Ntok) / 256;  // 16
    int base = tid * per;
    int c[NE];
#pragma unroll
    for (int e = 0; e < NE; e++) c[e] = 0;
    int eloc[16];
    for (int i = 0; i < per; i++) {
        int j = base + i;
        int t = j & (Ntok - 1);
        int2 ex = experts[t];
        int e = (j >= Ntok) ? ex.y : ex.x;
        eloc[i] = e;
        c[e]++;
    }
#pragma unroll
    for (int e = 0; e < NE; e++) cnts[tid][e] = c[e];
    __syncthreads();
    if (tid < NE) {
        int run = 0;
        for (int t2 = 0; t2 < 256; t2++) { int v = cnts[t2][tid]; cnts[t2][tid] = run; run += v; }
    }
    __syncthreads();
    int b[NE];
#pragma unroll
    for (int e = 0; e < NE; e++) b[e] = cnts[tid][e];
    for (int i = 0; i < per; i++) {
        int j = base + i;
        int t = j & (Ntok - 1);
        int e = eloc[i];
        int pos = b[e]++;
        if (pos < CAP) {
            int d = e * CAP + pos;
            dest[j] = d;
            slot_token[d] = t;
        } else {
            dest[j] = -1;
        }
    }
}

// ---------------- dispatch: gather tokens into bf16 buffer ----------------
__global__ __launch_bounds__(256) void dispatch_k(const float* __restrict__ x,
                                                  const int* __restrict__ slot_token,
                                                  __bf16* __restrict__ buf) {
    int slot = blockIdx.x;
    int tok = slot_token[slot];
    int idx = threadIdx.x * 8;
    __bf16* drow = buf + (size_t)slot * HD + idx;
    if (tok >= 0) {
        const float* srow = x + (size_t)tok * HD + idx;
        f32x4 a = *(const f32x4*)srow;
        f32x4 b = *(const f32x4*)(srow + 4);
        bf16x8 o;
        o[0] = (__bf16)a[0]; o[1] = (__bf16)a[1]; o[2] = (__bf16)a[2]; o[3] = (__bf16)a[3];
        o[4] = (__bf16)b[0]; o[5] = (__bf16)b[1]; o[6] = (__bf16)b[2]; o[7] = (__bf16)b[3];
        *(bf16x8*)drow = o;
    } else {
        f32x4 z = 0;
        *(f32x4*)drow = z;
    }
}

__device__ inline float gelu_exact(float v) {
    return 0.5f * v * (1.0f + erff(v * 0.70710678118654752f));
}

// ---------------- NT GEMM, m97 structure: global_load_lds w=16, linear LDS ----------------
// C[M,N] = A[M,K] * B[N,K]^T.  EPI=0: (bf16)gelu(x+bias)  EPI=1: (f32)(x+bias)
template <int EPI>
__global__ __launch_bounds__(256) void gemm_nt(const __bf16* __restrict__ A,
                                               const __bf16* __restrict__ B,
                                               const float* __restrict__ bias,
                                               void* __restrict__ Cout,
                                               int M, int N, int K) {
    __shared__ __align__(16) __bf16 As[128 * 64];
    __shared__ __align__(16) __bf16 Bs[128 * 64];
    int m0 = blockIdx.y * 128, n0 = blockIdx.x * 128;
    int tid = threadIdx.x;
    int lane = tid & 63;
    int wave = tid >> 6;
    int wr = wave >> 1, wc = wave & 1;
    int lrow = lane & 15, lk = (lane >> 4) * 8;

    // staging: round i covers LDS bytes [i*4096 + tid*16, +16) = rows i*32 + tid/8
    int sr = tid >> 3;            // 0..31
    int sc = (tid & 7) * 8;       // bf16 col
    const __bf16* Ag = A + (size_t)(m0 + sr) * K + sc;
    const __bf16* Bg = B + (size_t)(n0 + sr) * K + sc;
    __bf16* Al = As + sr * 64 + sc;
    __bf16* Bl = Bs + sr * 64 + sc;

    f32x4 acc[4][4];
#pragma unroll
    for (int m = 0; m < 4; m++)
#pragma unroll
        for (int n = 0; n < 4; n++) acc[m][n] = 0;

    for (int kt = 0; kt < K; kt += 64) {
#pragma unroll
        for (int i = 0; i < 4; i++) {
            gload_lds16(Ag + (size_t)(i * 32) * K + kt, Al + i * 2048);
            gload_lds16(Bg + (size_t)(i * 32) * K + kt, Bl + i * 2048);
        }
        __syncthreads();  // compiler drains vmcnt(0) before s_barrier
#pragma unroll
        for (int kk = 0; kk < 2; kk++) {
            bf16x8 af[4], bfr[4];
            int kb = kk * 32 + lk;
#pragma unroll
            for (int m = 0; m < 4; m++)
                af[m] = *(const bf16x8*)&As[(wr * 64 + m * 16 + lrow) * 64 + kb];
#pragma unroll
            for (int n = 0; n < 4; n++)
                bfr[n] = *(const bf16x8*)&Bs[(wc * 64 + n * 16 + lrow) * 64 + kb];
#pragma unroll
            for (int m = 0; m < 4; m++)
#pragma unroll
                for (int n = 0; n < 4; n++)
                    acc[m][n] = __builtin_amdgcn_mfma_f32_16x16x32_bf16(
                        af[m], bfr[n], acc[m][n], 0, 0, 0);
        }
        __syncthreads();
    }

    int col_base = n0 + wc * 64;
    int row_base = m0 + wr * 64 + (lane >> 4) * 4;
#pragma unroll
    for (int n = 0; n < 4; n++) {
        int col = col_base + n * 16 + lrow;
        float bv = bias[col];
#pragma unroll
        for (int m = 0; m < 4; m++) {
            int row0 = row_base + m * 16;
#pragma unroll
            for (int r = 0; r < 4; r++) {
                float v = acc[m][n][r] + bv;
                if (EPI == 0) {
                    ((__bf16*)Cout)[(size_t)(row0 + r) * N + col] = (__bf16)gelu_exact(v);
                } else {
                    ((float*)Cout)[(size_t)(row0 + r) * N + col] = v;
                }
            }
        }
    }
}

// ---------------- combine: out[t] = p0*h2[d0] + p1*h2[d1] ----------------
__global__ __launch_bounds__(256) void combine_k(const float* __restrict__ h2,
                                                 const int* __restrict__ dest,
                                                 const float2* __restrict__ probs,
                                                 float* __restrict__ out, int Ntok) {
    int t = blockIdx.x;
    int d0 = dest[t], d1 = dest[Ntok + t];
    float2 p = probs[t];
    int idx = threadIdx.x * 8;
    f32x4 o0 = 0, o1 = 0;
    if (d0 >= 0) {
        const float* r = h2 + (size_t)d0 * HD + idx;
        o0 += p.x * (*(const f32x4*)r);
        o1 += p.x * (*(const f32x4*)(r + 4));
    }
    if (d1 >= 0) {
        const float* r = h2 + (size_t)d1 * HD + idx;
        o0 += p.y * (*(const f32x4*)r);
        o1 += p.y * (*(const f32x4*)(r + 4));
    }
    float* w = out + (size_t)t * HD + idx;
    *(f32x4*)w = o0;
    *(f32x4*)(w + 4) = o1;
}

extern "C" void kernel_launch(void* const* d_in, const int* in_sizes, int n_in,
                              void* d_out, int out_size, void* d_ws, size_t ws_size,
                              hipStream_t stream) {
    const float* x  = (const float*)d_in[0];
    const float* rw = (const float*)d_in[1];
    const float* w1 = (const float*)d_in[2];
    const float* b1 = (const float*)d_in[3];
    const float* w2 = (const float*)d_in[4];
    const float* b2 = (const float*)d_in[5];
    float* out = (float*)d_out;
    int Ntok = in_sizes[0] / HD;  // 2048

    char* ws = (char*)d_ws;
    __bf16* w1b = (__bf16*)ws;            ws += (size_t)FD * HD * 2;
    __bf16* w2b = (__bf16*)ws;            ws += (size_t)HD * FD * 2;
    __bf16* buf = (__bf16*)ws;            ws += (size_t)NE * CAP * HD * 2;
    __bf16* h1  = (__bf16*)ws;            ws += (size_t)NE * CAP * FD * 2;
    float*  h2  = (float*)ws;             ws += (size_t)NE * CAP * HD * 4;
    int2*   experts = (int2*)ws;          ws += (size_t)Ntok * 8;
    float2* probsb  = (float2*)ws;        ws += (size_t)Ntok * 8;
    int*    dest    = (int*)ws;           ws += (size_t)2 * Ntok * 4;
    int*    slot_token = (int*)ws;        ws += (size_t)NE * CAP * 4;

    int n8 = FD * HD / 8;
    cvt_k<<<n8 / 256, 256, 0, stream>>>(w1, w1b, n8);
    cvt_k<<<n8 / 256, 256, 0, stream>>>(w2, w2b, n8);
    router_k<<<Ntok / 4, 256, 0, stream>>>(x, rw, experts, probsb, Ntok);
    scan_k<<<1, 256, 0, stream>>>(experts, dest, slot_token, Ntok);
    dispatch_k<<<NE * CAP, 256, 0, stream>>>(x, slot_token, buf);
    gemm_nt<0><<<dim3(FD / 128, (NE * CAP) / 128), 256, 0, stream>>>(
        buf, w1b, b1, (void*)h1, NE * CAP, FD, HD);
    gemm_nt<1><<<dim3(HD / 128, (NE * CAP) / 128), 256, 0, stream>>>(
        h1, w2b, b2, (void*)h2, NE * CAP, HD, FD);
    combine_k<<<Ntok, 256, 0, stream>>>(h2, dest, probsb, out, Ntok);
}

// Round 3
// 540.811 us; speedup vs baseline: 1.1305x; 1.1305x over previous
//
#include <hip/hip_runtime.h>

#define HD 2048
#define FD 8192
#define NE 8
#define CAP 512

typedef __attribute__((ext_vector_type(4))) float f32x4;
typedef __attribute__((ext_vector_type(8))) __bf16 bf16x8;

__device__ __forceinline__ void gload_lds16(const __bf16* g, __bf16* l) {
    __builtin_amdgcn_global_load_lds(
        (const __attribute__((address_space(1))) void*)g,
        (__attribute__((address_space(3))) void*)l, 16, 0, 0);
}

// ---------------- weight f32 -> bf16 conversion ----------------
__global__ __launch_bounds__(256) void cvt_k(const float* __restrict__ src,
                                             __bf16* __restrict__ dst, int n8) {
    int i = blockIdx.x * 256 + threadIdx.x;
    if (i >= n8) return;
    const float* s = src + (size_t)i * 8;
    f32x4 a = *(const f32x4*)s;
    f32x4 b = *(const f32x4*)(s + 4);
    bf16x8 o;
    o[0] = (__bf16)a[0]; o[1] = (__bf16)a[1]; o[2] = (__bf16)a[2]; o[3] = (__bf16)a[3];
    o[4] = (__bf16)b[0]; o[5] = (__bf16)b[1]; o[6] = (__bf16)b[2]; o[7] = (__bf16)b[3];
    *(bf16x8*)(dst + (size_t)i * 8) = o;
}

// ---------------- router: f64 logits, f32-prob top-2 with index tie-break ----------------
__global__ __launch_bounds__(256) void router_k(const float* __restrict__ x,
                                                const float* __restrict__ rw,
                                                int2* __restrict__ experts,
                                                float2* __restrict__ probs, int Ntok) {
    int wave = threadIdx.x >> 6, lane = threadIdx.x & 63;
    int n = blockIdx.x * 4 + wave;
    if (n >= Ntok) return;
    const float* xr = x + (size_t)n * HD;
    double acc[NE];
#pragma unroll
    for (int e = 0; e < NE; e++) acc[e] = 0.0;
    for (int i = 0; i < HD / 64; i++) {
        float xv = xr[lane + 64 * i];
#pragma unroll
        for (int e = 0; e < NE; e++)
            acc[e] += (double)xv * (double)rw[e * HD + lane + 64 * i];
    }
#pragma unroll
    for (int e = 0; e < NE; e++) {
        double v = acc[e];
        for (int off = 32; off > 0; off >>= 1) v += __shfl_xor(v, off);
        acc[e] = v;
    }
    if (lane == 0) {
        double mx = acc[0];
#pragma unroll
        for (int e = 1; e < NE; e++) mx = acc[e] > mx ? acc[e] : mx;
        double s = 0.0;
#pragma unroll
        for (int e = 0; e < NE; e++) s += exp(acc[e] - mx);
        float pf[NE];
#pragma unroll
        for (int e = 0; e < NE; e++) pf[e] = (float)(exp(acc[e] - mx) / s);
        int e0 = 0; float b0 = pf[0];
#pragma unroll
        for (int e = 1; e < NE; e++) if (pf[e] > b0) { b0 = pf[e]; e0 = e; }
        int e1 = -1; float b1 = -1.0f;
#pragma unroll
        for (int e = 0; e < NE; e++) if (e != e0 && pf[e] > b1) { b1 = pf[e]; e1 = e; }
        experts[n] = make_int2(e0, e1);
        probs[n] = make_float2(b0, b1);
    }
}

// ---------------- capacity scan (slot-major order), single block ----------------
__global__ __launch_bounds__(256) void scan_k(const int2* __restrict__ experts,
                                              int* __restrict__ dest,
                                              int* __restrict__ slot_token, int Ntok) {
    __shared__ int cnts[256][NE];
    int tid = threadIdx.x;
    for (int i = tid; i < NE * CAP; i += 256) slot_token[i] = -1;
    int per = (2 * Ntok) / 256;  // 16
    int base = tid * per;
    int c[NE];
#pragma unroll
    for (int e = 0; e < NE; e++) c[e] = 0;
    int eloc[16];
    for (int i = 0; i < per; i++) {
        int j = base + i;
        int t = j & (Ntok - 1);
        int2 ex = experts[t];
        int e = (j >= Ntok) ? ex.y : ex.x;
        eloc[i] = e;
        c[e]++;
    }
#pragma unroll
    for (int e = 0; e < NE; e++) cnts[tid][e] = c[e];
    __syncthreads();
    if (tid < NE) {
        int run = 0;
        for (int t2 = 0; t2 < 256; t2++) { int v = cnts[t2][tid]; cnts[t2][tid] = run; run += v; }
    }
    __syncthreads();
    int b[NE];
#pragma unroll
    for (int e = 0; e < NE; e++) b[e] = cnts[tid][e];
    for (int i = 0; i < per; i++) {
        int j = base + i;
        int t = j & (Ntok - 1);
        int e = eloc[i];
        int pos = b[e]++;
        if (pos < CAP) {
            int d = e * CAP + pos;
            dest[j] = d;
            slot_token[d] = t;
        } else {
            dest[j] = -1;
        }
    }
}

// ---------------- dispatch: gather tokens into bf16 buffer ----------------
__global__ __launch_bounds__(256) void dispatch_k(const float* __restrict__ x,
                                                  const int* __restrict__ slot_token,
                                                  __bf16* __restrict__ buf) {
    int slot = blockIdx.x;
    int tok = slot_token[slot];
    int idx = threadIdx.x * 8;
    __bf16* drow = buf + (size_t)slot * HD + idx;
    if (tok >= 0) {
        const float* srow = x + (size_t)tok * HD + idx;
        f32x4 a = *(const f32x4*)srow;
        f32x4 b = *(const f32x4*)(srow + 4);
        bf16x8 o;
        o[0] = (__bf16)a[0]; o[1] = (__bf16)a[1]; o[2] = (__bf16)a[2]; o[3] = (__bf16)a[3];
        o[4] = (__bf16)b[0]; o[5] = (__bf16)b[1]; o[6] = (__bf16)b[2]; o[7] = (__bf16)b[3];
        *(bf16x8*)drow = o;
    } else {
        f32x4 z = 0;
        *(f32x4*)drow = z;
    }
}

__device__ inline float gelu_exact(float v) {
    return 0.5f * v * (1.0f + erff(v * 0.70710678118654752f));
}

// ---------------- NT GEMM, m97 structure + XOR chunk swizzle (rule #21) ----------------
// LDS[row][chunk j] = global[row][chunk j ^ (row&7)]  (chunk = 8 bf16 = 16B)
// write side: linear LDS dest, per-lane pre-swizzled global source
// read side:  chunk' = chunk ^ (row&7)
// C[M,N] = A[M,K] * B[N,K]^T.  EPI=0: (bf16)gelu(x+bias)  EPI=1: (f32)(x+bias)
template <int EPI>
__global__ __launch_bounds__(256) void gemm_nt(const __bf16* __restrict__ A,
                                               const __bf16* __restrict__ B,
                                               const float* __restrict__ bias,
                                               void* __restrict__ Cout,
                                               int M, int N, int K) {
    __shared__ __align__(16) __bf16 As[128 * 64];
    __shared__ __align__(16) __bf16 Bs[128 * 64];
    int m0 = blockIdx.y * 128, n0 = blockIdx.x * 128;
    int tid = threadIdx.x;
    int lane = tid & 63;
    int wave = tid >> 6;
    int wr = wave >> 1, wc = wave & 1;
    int lrow = lane & 15;

    // staging: round i covers LDS rows i*32 + tid/8 (linear dest), global source
    // chunk XOR-swizzled by row&7 (= (tid>>3)&7, invariant under +32-row strides)
    int sr = tid >> 3;                                   // 0..31
    int scs = (((tid & 7) ^ ((tid >> 3) & 7)) * 8);      // swizzled source chunk (bf16 col)
    int scl = (tid & 7) * 8;                             // linear LDS chunk (bf16 col)
    const __bf16* Ag = A + (size_t)(m0 + sr) * K + scs;
    const __bf16* Bg = B + (size_t)(n0 + sr) * K + scs;
    __bf16* Al = As + sr * 64 + scl;
    __bf16* Bl = Bs + sr * 64 + scl;

    f32x4 acc[4][4];
#pragma unroll
    for (int m = 0; m < 4; m++)
#pragma unroll
        for (int n = 0; n < 4; n++) acc[m][n] = 0;

    for (int kt = 0; kt < K; kt += 64) {
#pragma unroll
        for (int i = 0; i < 4; i++) {
            gload_lds16(Ag + (size_t)(i * 32) * K + kt, Al + i * 2048);
            gload_lds16(Bg + (size_t)(i * 32) * K + kt, Bl + i * 2048);
        }
        __syncthreads();
#pragma unroll
        for (int kk = 0; kk < 2; kk++) {
            bf16x8 af[4], bfr[4];
            // fragment wants global chunk (kk*4 + lane>>4) of row (..+lrow);
            // stored at LDS chunk (kk*4 + lane>>4) ^ (row&7), row&7 == lane&7
            int swzk = ((kk * 4 + (lane >> 4)) ^ (lane & 7)) * 8;
#pragma unroll
            for (int m = 0; m < 4; m++)
                af[m] = *(const bf16x8*)&As[(wr * 64 + m * 16 + lrow) * 64 + swzk];
#pragma unroll
            for (int n = 0; n < 4; n++)
                bfr[n] = *(const bf16x8*)&Bs[(wc * 64 + n * 16 + lrow) * 64 + swzk];
#pragma unroll
            for (int m = 0; m < 4; m++)
#pragma unroll
                for (int n = 0; n < 4; n++)
                    acc[m][n] = __builtin_amdgcn_mfma_f32_16x16x32_bf16(
                        af[m], bfr[n], acc[m][n], 0, 0, 0);
        }
        __syncthreads();
    }

    int col_base = n0 + wc * 64;
    int row_base = m0 + wr * 64 + (lane >> 4) * 4;
#pragma unroll
    for (int n = 0; n < 4; n++) {
        int col = col_base + n * 16 + lrow;
        float bv = bias[col];
#pragma unroll
        for (int m = 0; m < 4; m++) {
            int row0 = row_base + m * 16;
#pragma unroll
            for (int r = 0; r < 4; r++) {
                float v = acc[m][n][r] + bv;
                if (EPI == 0) {
                    ((__bf16*)Cout)[(size_t)(row0 + r) * N + col] = (__bf16)gelu_exact(v);
                } else {
                    ((float*)Cout)[(size_t)(row0 + r) * N + col] = v;
                }
            }
        }
    }
}

// ---------------- combine: out[t] = p0*h2[d0] + p1*h2[d1] ----------------
__global__ __launch_bounds__(256) void combine_k(const float* __restrict__ h2,
                                                 const int* __restrict__ dest,
                                                 const float2* __restrict__ probs,
                                                 float* __restrict__ out, int Ntok) {
    int t = blockIdx.x;
    int d0 = dest[t], d1 = dest[Ntok + t];
    float2 p = probs[t];
    int idx = threadIdx.x * 8;
    f32x4 o0 = 0, o1 = 0;
    if (d0 >= 0) {
        const float* r = h2 + (size_t)d0 * HD + idx;
        o0 += p.x * (*(const f32x4*)r);
        o1 += p.x * (*(const f32x4*)(r + 4));
    }
    if (d1 >= 0) {
        const float* r = h2 + (size_t)d1 * HD + idx;
        o0 += p.y * (*(const f32x4*)r);
        o1 += p.y * (*(const f32x4*)(r + 4));
    }
    float* w = out + (size_t)t * HD + idx;
    *(f32x4*)w = o0;
    *(f32x4*)(w + 4) = o1;
}

extern "C" void kernel_launch(void* const* d_in, const int* in_sizes, int n_in,
                              void* d_out, int out_size, void* d_ws, size_t ws_size,
                              hipStream_t stream) {
    const float* x  = (const float*)d_in[0];
    const float* rw = (const float*)d_in[1];
    const float* w1 = (const float*)d_in[2];
    const float* b1 = (const float*)d_in[3];
    const float* w2 = (const float*)d_in[4];
    const float* b2 = (const float*)d_in[5];
    float* out = (float*)d_out;
    int Ntok = in_sizes[0] / HD;  // 2048

    char* ws = (char*)d_ws;
    __bf16* w1b = (__bf16*)ws;            ws += (size_t)FD * HD * 2;
    __bf16* w2b = (__bf16*)ws;            ws += (size_t)HD * FD * 2;
    __bf16* buf = (__bf16*)ws;            ws += (size_t)NE * CAP * HD * 2;
    __bf16* h1  = (__bf16*)ws;            ws += (size_t)NE * CAP * FD * 2;
    float*  h2  = (float*)ws;             ws += (size_t)NE * CAP * HD * 4;
    int2*   experts = (int2*)ws;          ws += (size_t)Ntok * 8;
    float2* probsb  = (float2*)ws;        ws += (size_t)Ntok * 8;
    int*    dest    = (int*)ws;           ws += (size_t)2 * Ntok * 4;
    int*    slot_token = (int*)ws;        ws += (size_t)NE * CAP * 4;

    int n8 = FD * HD / 8;
    cvt_k<<<n8 / 256, 256, 0, stream>>>(w1, w1b, n8);
    cvt_k<<<n8 / 256, 256, 0, stream>>>(w2, w2b, n8);
    router_k<<<Ntok / 4, 256, 0, stream>>>(x, rw, experts, probsb, Ntok);
    scan_k<<<1, 256, 0, stream>>>(experts, dest, slot_token, Ntok);
    dispatch_k<<<NE * CAP, 256, 0, stream>>>(x, slot_token, buf);
    gemm_nt<0><<<dim3(FD / 128, (NE * CAP) / 128), 256, 0, stream>>>(
        buf, w1b, b1, (void*)h1, NE * CAP, FD, HD);
    gemm_nt<1><<<dim3(HD / 128, (NE * CAP) / 128), 256, 0, stream>>>(
        h1, w2b, b2, (void*)h2, NE * CAP, HD, FD);
    combine_k<<<Ntok, 256, 0, stream>>>(h2, dest, probsb, out, Ntok);
}

// Round 5
// 526.698 us; speedup vs baseline: 1.1608x; 1.0268x over previous
//
#include <hip/hip_runtime.h>

#define HD 2048
#define FD 8192
#define NE 8
#define CAP 512

typedef __attribute__((ext_vector_type(4))) float f32x4;
typedef __attribute__((ext_vector_type(8))) __bf16 bf16x8;

__device__ __forceinline__ void gload_lds16(const __bf16* g, __bf16* l) {
    __builtin_amdgcn_global_load_lds(
        (const __attribute__((address_space(1))) void*)g,
        (__attribute__((address_space(3))) void*)l, 16, 0, 0);
}
__device__ __forceinline__ void waitv4() { asm volatile("s_waitcnt vmcnt(4)" ::: "memory"); }
__device__ __forceinline__ void waitv0() { asm volatile("s_waitcnt vmcnt(0)" ::: "memory"); }

// ---------------- weight f32 -> bf16 conversion ----------------
__global__ __launch_bounds__(256) void cvt_k(const float* __restrict__ src,
                                             __bf16* __restrict__ dst, int n8) {
    int i = blockIdx.x * 256 + threadIdx.x;
    if (i >= n8) return;
    const float* s = src + (size_t)i * 8;
    f32x4 a = *(const f32x4*)s;
    f32x4 b = *(const f32x4*)(s + 4);
    bf16x8 o;
    o[0] = (__bf16)a[0]; o[1] = (__bf16)a[1]; o[2] = (__bf16)a[2]; o[3] = (__bf16)a[3];
    o[4] = (__bf16)b[0]; o[5] = (__bf16)b[1]; o[6] = (__bf16)b[2]; o[7] = (__bf16)b[3];
    *(bf16x8*)(dst + (size_t)i * 8) = o;
}

// ---------------- router: f64 logits, f32-prob top-2 with index tie-break ----------------
__global__ __launch_bounds__(256) void router_k(const float* __restrict__ x,
                                                const float* __restrict__ rw,
                                                int2* __restrict__ experts,
                                                float2* __restrict__ probs, int Ntok) {
    int wave = threadIdx.x >> 6, lane = threadIdx.x & 63;
    int n = blockIdx.x * 4 + wave;
    if (n >= Ntok) return;
    const float* xr = x + (size_t)n * HD;
    double acc[NE];
#pragma unroll
    for (int e = 0; e < NE; e++) acc[e] = 0.0;
    for (int i = 0; i < HD / 64; i++) {
        float xv = xr[lane + 64 * i];
#pragma unroll
        for (int e = 0; e < NE; e++)
            acc[e] += (double)xv * (double)rw[e * HD + lane + 64 * i];
    }
#pragma unroll
    for (int e = 0; e < NE; e++) {
        double v = acc[e];
        for (int off = 32; off > 0; off >>= 1) v += __shfl_xor(v, off);
        acc[e] = v;
    }
    if (lane == 0) {
        double mx = acc[0];
#pragma unroll
        for (int e = 1; e < NE; e++) mx = acc[e] > mx ? acc[e] : mx;
        double s = 0.0;
#pragma unroll
        for (int e = 0; e < NE; e++) s += exp(acc[e] - mx);
        float pf[NE];
#pragma unroll
        for (int e = 0; e < NE; e++) pf[e] = (float)(exp(acc[e] - mx) / s);
        int e0 = 0; float b0 = pf[0];
#pragma unroll
        for (int e = 1; e < NE; e++) if (pf[e] > b0) { b0 = pf[e]; e0 = e; }
        int e1 = -1; float b1 = -1.0f;
#pragma unroll
        for (int e = 0; e < NE; e++) if (e != e0 && pf[e] > b1) { b1 = pf[e]; e1 = e; }
        experts[n] = make_int2(e0, e1);
        probs[n] = make_float2(b0, b1);
    }
}

// ---------------- capacity scan (slot-major order), single block ----------------
__global__ __launch_bounds__(256) void scan_k(const int2* __restrict__ experts,
                                              int* __restrict__ dest,
                                              int* __restrict__ slot_token, int Ntok) {
    __shared__ int cnts[256][NE];
    int tid = threadIdx.x;
    for (int i = tid; i < NE * CAP; i += 256) slot_token[i] = -1;
    int per = (2 * Ntok) / 256;  // 16
    int base = tid * per;
    int c[NE];
#pragma unroll
    for (int e = 0; e < NE; e++) c[e] = 0;
    int eloc[16];
    for (int i = 0; i < per; i++) {
        int j = base + i;
        int t = j & (Ntok - 1);
        int2 ex = experts[t];
        int e = (j >= Ntok) ? ex.y : ex.x;
        eloc[i] = e;
        c[e]++;
    }
#pragma unroll
    for (int e = 0; e < NE; e++) cnts[tid][e] = c[e];
    __syncthreads();
    if (tid < NE) {
        int run = 0;
        for (int t2 = 0; t2 < 256; t2++) { int v = cnts[t2][tid]; cnts[t2][tid] = run; run += v; }
    }
    __syncthreads();
    int b[NE];
#pragma unroll
    for (int e = 0; e < NE; e++) b[e] = cnts[tid][e];
    for (int i = 0; i < per; i++) {
        int j = base + i;
        int t = j & (Ntok - 1);
        int e = eloc[i];
        int pos = b[e]++;
        if (pos < CAP) {
            int d = e * CAP + pos;
            dest[j] = d;
            slot_token[d] = t;
        } else {
            dest[j] = -1;
        }
    }
}

// ---------------- dispatch: gather tokens into bf16 buffer ----------------
__global__ __launch_bounds__(256) void dispatch_k(const float* __restrict__ x,
                                                  const int* __restrict__ slot_token,
                                                  __bf16* __restrict__ buf) {
    int slot = blockIdx.x;
    int tok = slot_token[slot];
    int idx = threadIdx.x * 8;
    __bf16* drow = buf + (size_t)slot * HD + idx;
    if (tok >= 0) {
        const float* srow = x + (size_t)tok * HD + idx;
        f32x4 a = *(const f32x4*)srow;
        f32x4 b = *(const f32x4*)(srow + 4);
        bf16x8 o;
        o[0] = (__bf16)a[0]; o[1] = (__bf16)a[1]; o[2] = (__bf16)a[2]; o[3] = (__bf16)a[3];
        o[4] = (__bf16)b[0]; o[5] = (__bf16)b[1]; o[6] = (__bf16)b[2]; o[7] = (__bf16)b[3];
        *(bf16x8*)drow = o;
    } else {
        f32x4 z = 0;
        *(f32x4*)drow = z;
    }
}

__device__ inline float gelu_exact(float v) {
    return 0.5f * v * (1.0f + erff(v * 0.70710678118654752f));
}

// =====================================================================
// 8-phase 256-wide NT GEMM (T2 swizzle + T3/T4 counted vmcnt + T5 setprio)
// C[M,N] = A[M,K]*B[N,K]^T.  8 waves as 2(M)x4(N); wave tile (BM/2)x64.
// BN=256 fixed. BM=256 (QM=2, ALOADS=4) or BM=128 (QM=1, ALOADS=2).
// LDS: As[2][BM][64], Bs[2][256][64], chunk-XOR swizzled (proven, 0 conflicts).
// Per K-tile: 4 phases = acc-quadrant q; B-frags front-loaded at q0.
// Staging: A(t+1) at q0/q1 (other buffer, idle since t-1's end barrier);
//          B(t+2) at q2/q3 (current buffer's B region, consumed at q0 barrier).
// One counted vmcnt(4) per tile at q3 (vmcnt(0) only at t = NT-2).
// EPI=0: (bf16)gelu(x+bias)   EPI=1: (f32)(x+bias)
// =====================================================================
template <int EPI, int BM, int ALOADS, int QM>
__global__ __launch_bounds__(512) void gemm8p(const __bf16* __restrict__ A,
                                              const __bf16* __restrict__ B,
                                              const float* __restrict__ bias,
                                              void* __restrict__ Cout,
                                              int N, int K) {
    constexpr int MREP = 4 * QM;
    __shared__ __align__(16) __bf16 As[2][BM * 64];
    __shared__ __align__(16) __bf16 Bs[2][256 * 64];
    int m0 = blockIdx.y * BM, n0 = blockIdx.x * 256;
    int tid = threadIdx.x;
    int lane = tid & 63, wave = tid >> 6;
    int wr = wave >> 2, wc = wave & 3;  // 2 x 4
    int lrow = lane & 15, l16 = lane >> 4;
    int NT = K >> 6;

    // --- staging addressing (chunk = 16B = 8 bf16) ---
    int sr = tid >> 3;                       // 0..63 (row within 64-row group)
    int c8 = tid & 7;                        // linear LDS chunk
    int csw = (c8 ^ (sr & 7)) * 8;           // pre-swizzled global source chunk
    const __bf16* Ag = A + (size_t)(m0 + sr) * K + csw;
    const __bf16* Bg = B + (size_t)(n0 + sr) * K + csw;
    int ldst = sr * 64 + c8 * 8;             // linear LDS offset

    // --- read-side swizzled K-chunks (row&7 == lrow&7 for all fragments) ---
    int rch0 = ((0 + l16) ^ (lrow & 7)) * 8;
    int rch1 = ((4 + l16) ^ (lrow & 7)) * 8;

    f32x4 acc[MREP][4];
#pragma unroll
    for (int m = 0; m < MREP; m++)
#pragma unroll
        for (int n = 0; n < 4; n++) acc[m][n] = 0;

    // --- prologue: A(0), B(0), B(1); leave B(1) in flight ---
#pragma unroll
    for (int i = 0; i < ALOADS; i++)
        gload_lds16(Ag + (size_t)(i * 64) * K, &As[0][ldst + i * 4096]);
#pragma unroll
    for (int i = 0; i < 4; i++)
        gload_lds16(Bg + (size_t)(i * 64) * K, &Bs[0][ldst + i * 4096]);
#pragma unroll
    for (int i = 0; i < 4; i++)
        gload_lds16(Bg + (size_t)(i * 64) * K + 64, &Bs[1][ldst + i * 4096]);
    waitv4();
    __builtin_amdgcn_s_barrier();

    for (int t = 0; t < NT; ++t) {
        int p = t & 1;
        const __bf16* Asl = As[p];
        const __bf16* Bsl = Bs[p];
        bf16x8 bf[4][2];
#pragma unroll
        for (int q = 0; q < 4; ++q) {
            // ds-read this phase's A quadrant
            bf16x8 af[QM][2];
#pragma unroll
            for (int j = 0; j < QM; j++) {
                int row = (wr * (BM / 2) + (q * QM + j) * 16 + lrow) * 64;
                af[j][0] = *(const bf16x8*)&Asl[row + rch0];
                af[j][1] = *(const bf16x8*)&Asl[row + rch1];
            }
            if (q == 0) {
                // front-load ALL B fragments for this tile
#pragma unroll
                for (int n = 0; n < 4; n++) {
                    int row = (wc * 64 + n * 16 + lrow) * 64;
                    bf[n][0] = *(const bf16x8*)&Bsl[row + rch0];
                    bf[n][1] = *(const bf16x8*)&Bsl[row + rch1];
                }
                if (t + 1 < NT) {
                    gload_lds16(Ag + (size_t)(t + 1) * 64, &As[(t + 1) & 1][ldst]);
                    gload_lds16(Ag + (size_t)64 * K + (size_t)(t + 1) * 64,
                                &As[(t + 1) & 1][ldst + 4096]);
                }
            } else if (q == 1) {
                if (ALOADS == 4 && t + 1 < NT) {
                    gload_lds16(Ag + (size_t)128 * K + (size_t)(t + 1) * 64,
                                &As[(t + 1) & 1][ldst + 8192]);
                    gload_lds16(Ag + (size_t)192 * K + (size_t)(t + 1) * 64,
                                &As[(t + 1) & 1][ldst + 12288]);
                }
            } else if (q == 2) {
                if (t + 2 < NT) {
                    gload_lds16(Bg + (size_t)(t + 2) * 64, &Bs[t & 1][ldst]);
                    gload_lds16(Bg + (size_t)64 * K + (size_t)(t + 2) * 64,
                                &Bs[t & 1][ldst + 4096]);
                }
            } else {
                if (t + 2 < NT) {
                    gload_lds16(Bg + (size_t)128 * K + (size_t)(t + 2) * 64,
                                &Bs[t & 1][ldst + 8192]);
                    gload_lds16(Bg + (size_t)192 * K + (size_t)(t + 2) * 64,
                                &Bs[t & 1][ldst + 12288]);
                }
            }
            __builtin_amdgcn_s_barrier();
            __builtin_amdgcn_s_setprio(1);
#pragma unroll
            for (int j = 0; j < QM; j++)
#pragma unroll
                for (int n = 0; n < 4; n++)
#pragma unroll
                    for (int kk = 0; kk < 2; kk++)
                        acc[q * QM + j][n] = __builtin_amdgcn_mfma_f32_16x16x32_bf16(
                            af[j][kk], bf[n][kk], acc[q * QM + j][n], 0, 0, 0);
            __builtin_amdgcn_s_setprio(0);
            if (q == 3) {
                if (t + 2 < NT) waitv4(); else waitv0();
            }
            __builtin_amdgcn_s_barrier();
        }
    }

    // --- epilogue ---
    int col_base = n0 + wc * 64;
    int row_base0 = m0 + wr * (BM / 2) + l16 * 4;
#pragma unroll
    for (int n = 0; n < 4; n++) {
        int col = col_base + n * 16 + lrow;
        float bv = bias[col];
#pragma unroll
        for (int mf = 0; mf < MREP; mf++) {
            int row0 = row_base0 + mf * 16;
#pragma unroll
            for (int r = 0; r < 4; r++) {
                float v = acc[mf][n][r] + bv;
                if (EPI == 0) {
                    ((__bf16*)Cout)[(size_t)(row0 + r) * N + col] = (__bf16)gelu_exact(v);
                } else {
                    ((float*)Cout)[(size_t)(row0 + r) * N + col] = v;
                }
            }
        }
    }
}

// ---------------- combine: out[t] = p0*h2[d0] + p1*h2[d1] ----------------
__global__ __launch_bounds__(256) void combine_k(const float* __restrict__ h2,
                                                 const int* __restrict__ dest,
                                                 const float2* __restrict__ probs,
                                                 float* __restrict__ out, int Ntok) {
    int t = blockIdx.x;
    int d0 = dest[t], d1 = dest[Ntok + t];
    float2 p = probs[t];
    int idx = threadIdx.x * 8;
    f32x4 o0 = 0, o1 = 0;
    if (d0 >= 0) {
        const float* r = h2 + (size_t)d0 * HD + idx;
        o0 += p.x * (*(const f32x4*)r);
        o1 += p.x * (*(const f32x4*)(r + 4));
    }
    if (d1 >= 0) {
        const float* r = h2 + (size_t)d1 * HD + idx;
        o0 += p.y * (*(const f32x4*)r);
        o1 += p.y * (*(const f32x4*)(r + 4));
    }
    float* w = out + (size_t)t * HD + idx;
    *(f32x4*)w = o0;
    *(f32x4*)(w + 4) = o1;
}

extern "C" void kernel_launch(void* const* d_in, const int* in_sizes, int n_in,
                              void* d_out, int out_size, void* d_ws, size_t ws_size,
                              hipStream_t stream) {
    const float* x  = (const float*)d_in[0];
    const float* rw = (const float*)d_in[1];
    const float* w1 = (const float*)d_in[2];
    const float* b1 = (const float*)d_in[3];
    const float* w2 = (const float*)d_in[4];
    const float* b2 = (const float*)d_in[5];
    float* out = (float*)d_out;
    int Ntok = in_sizes[0] / HD;  // 2048

    char* ws = (char*)d_ws;
    __bf16* w1b = (__bf16*)ws;            ws += (size_t)FD * HD * 2;
    __bf16* w2b = (__bf16*)ws;            ws += (size_t)HD * FD * 2;
    __bf16* buf = (__bf16*)ws;            ws += (size_t)NE * CAP * HD * 2;
    __bf16* h1  = (__bf16*)ws;            ws += (size_t)NE * CAP * FD * 2;
    float*  h2  = (float*)ws;             ws += (size_t)NE * CAP * HD * 4;
    int2*   experts = (int2*)ws;          ws += (size_t)Ntok * 8;
    float2* probsb  = (float2*)ws;        ws += (size_t)Ntok * 8;
    int*    dest    = (int*)ws;           ws += (size_t)2 * Ntok * 4;
    int*    slot_token = (int*)ws;        ws += (size_t)NE * CAP * 4;

    int n8 = FD * HD / 8;
    cvt_k<<<n8 / 256, 256, 0, stream>>>(w1, w1b, n8);
    cvt_k<<<n8 / 256, 256, 0, stream>>>(w2, w2b, n8);
    router_k<<<Ntok / 4, 256, 0, stream>>>(x, rw, experts, probsb, Ntok);
    scan_k<<<1, 256, 0, stream>>>(experts, dest, slot_token, Ntok);
    dispatch_k<<<NE * CAP, 256, 0, stream>>>(x, slot_token, buf);
    // GEMM1: [4096,2048] x [8192,2048]^T  -> 16x32 = 512 blocks, BM=256
    gemm8p<0, 256, 4, 2><<<dim3(FD / 256, (NE * CAP) / 256), 512, 0, stream>>>(
        buf, w1b, b1, (void*)h1, FD, HD);
    // GEMM2: [4096,8192] x [2048,8192]^T  -> 8x32 = 256 blocks, BM=128
    gemm8p<1, 128, 2, 1><<<dim3(HD / 256, (NE * CAP) / 128), 512, 0, stream>>>(
        h1, w2b, b2, (void*)h2, HD, FD);
    combine_k<<<Ntok, 256, 0, stream>>>(h2, dest, probsb, out, Ntok);
}